// Round 1
// baseline (461.440 us; speedup 1.0000x reference)
//
#include <hip/hip_runtime.h>
#include <hip/hip_bf16.h>

// Problem: B=64, S=1024, H=1024, A=512, E=512
// scores = tanh(encoded@W_enc + b_enc + states@W_dec + b_dec) . w_out  (+b_out, softmax-invariant)
// weights = softmax(scores); attention = weights . encoded
// GRU: x=[inputs,attention]; gi=x@W_ih+b_ih; gh=states@W_hh+b_hh; gates -> h_new

typedef __attribute__((ext_vector_type(8))) __bf16 bf16x8;
typedef __attribute__((ext_vector_type(4))) float f32x4;

#define LDK 40  // 32 k + 8 pad bf16 -> 80B row stride, 16B aligned, ~2-4 way banks

__device__ __forceinline__ float fast_tanh(float x) {
  float xa = fminf(fmaxf(x, -15.f), 15.f);
  float e = __expf(2.f * xa);
  return (e - 1.f) / (e + 1.f);
}

// ---------------- Kernel A: addv[b][a] = b_enc[a]+b_dec[a]+sum_h states[b,h]*W_dec[h,a]
__global__ __launch_bounds__(256) void dec_proj_kernel(
    const float* __restrict__ states, const float* __restrict__ W_dec,
    const float* __restrict__ b_enc, const float* __restrict__ b_dec,
    float* __restrict__ addv) {
  int b = blockIdx.x, tid = threadIdx.x;
  __shared__ float sl[1024];
  for (int i = tid; i < 1024; i += 256) sl[i] = states[b * 1024 + i];
  __syncthreads();
  int a0 = tid, a1 = tid + 256;
  float acc0 = b_enc[a0] + b_dec[a0];
  float acc1 = b_enc[a1] + b_dec[a1];
#pragma unroll 8
  for (int h = 0; h < 1024; ++h) {
    float s = sl[h];
    acc0 += s * W_dec[h * 512 + a0];
    acc1 += s * W_dec[h * 512 + a1];
  }
  addv[b * 512 + a0] = acc0;
  addv[b * 512 + a1] = acc1;
}

// ---------------- Kernel B: big MFMA GEMM + fused tanh/w_out row-reduction
// grid (bn=4, bm=512), 256 threads (4 waves 2x2), tile 128x128, BK=32
__global__ __launch_bounds__(256) void enc_score_kernel(
    const float* __restrict__ encoded,  // [65536][1024]
    const float* __restrict__ W_enc,    // [1024][512]
    const float* __restrict__ addv,     // [64][512]
    const float* __restrict__ w_out,    // [512]
    float* __restrict__ psc)            // [4][65536] partial scores per col-tile
{
  __shared__ __attribute__((aligned(16))) __bf16 As[2][128][LDK];
  __shared__ __attribute__((aligned(16))) __bf16 Bs[2][128][LDK];
  __shared__ float red[128][2];

  const int bn = blockIdx.x;   // 0..3 col tile
  const int bm = blockIdx.y;   // 0..511 row tile
  const int tid = threadIdx.x;
  const int lane = tid & 63;
  const int wid = tid >> 6;
  const int wrow = wid >> 1, wcol = wid & 1;
  const int lr = lane & 15;
  const int lkb = lane >> 4;   // 0..3

  const long row0 = (long)bm * 128;
  const int col0 = bn * 128;

  const int bcol = tid & 127;         // B staging: col within tile
  const int bkh = (tid >> 7) * 16;    // B staging: k half (0 or 16)

  f32x4 ra[4];
  float rbv[16];

  auto loadTiles = [&](int kt) {
    const float* abase = encoded + row0 * 1024 + kt * 32;
#pragma unroll
    for (int i = 0; i < 4; ++i) {
      int f = tid + 256 * i;
      ra[i] = *(const f32x4*)(abase + (f >> 3) * 1024 + (f & 7) * 4);
    }
    const float* bbase = W_enc + (long)(kt * 32 + bkh) * 512 + col0 + bcol;
#pragma unroll
    for (int j = 0; j < 16; ++j) rbv[j] = bbase[j * 512];
  };
  auto writeTiles = [&](int buf) {
#pragma unroll
    for (int i = 0; i < 4; ++i) {
      int f = tid + 256 * i;
      __bf16* p = &As[buf][f >> 3][(f & 7) * 4];
      p[0] = (__bf16)ra[i].x; p[1] = (__bf16)ra[i].y;
      p[2] = (__bf16)ra[i].z; p[3] = (__bf16)ra[i].w;
    }
    __bf16* q = &Bs[buf][bcol][bkh];
#pragma unroll
    for (int j = 0; j < 16; ++j) q[j] = (__bf16)rbv[j];
  };

  f32x4 acc[4][4];
#pragma unroll
  for (int m = 0; m < 4; ++m)
#pragma unroll
    for (int n = 0; n < 4; ++n) acc[m][n] = (f32x4){0.f, 0.f, 0.f, 0.f};

  loadTiles(0);
  writeTiles(0);
  int buf = 0;
  for (int kt = 0; kt < 32; ++kt) {
    __syncthreads();
    if (kt < 31) loadTiles(kt + 1);
    bf16x8 af[4], bfr[4];
#pragma unroll
    for (int m = 0; m < 4; ++m)
      af[m] = *(const bf16x8*)&As[buf][wrow * 64 + m * 16 + lr][lkb * 8];
#pragma unroll
    for (int n = 0; n < 4; ++n)
      bfr[n] = *(const bf16x8*)&Bs[buf][wcol * 64 + n * 16 + lr][lkb * 8];
#pragma unroll
    for (int m = 0; m < 4; ++m)
#pragma unroll
      for (int n = 0; n < 4; ++n)
        acc[m][n] = __builtin_amdgcn_mfma_f32_16x16x32_bf16(af[m], bfr[n], acc[m][n], 0, 0, 0);
    if (kt < 31) writeTiles(buf ^ 1);
    buf ^= 1;
  }

  // Epilogue: score partial per row = sum_col tanh(acc + addv[b][col]) * w_out[col]
  // C/D layout: col = lane&15, row = (lane>>4)*4 + reg   [guide m89]
  const int b = bm >> 3;  // 1024 rows per batch, 128 rows per block
  const float* addvb = addv + b * 512;
  float rowsum[4][4];
#pragma unroll
  for (int m = 0; m < 4; ++m)
#pragma unroll
    for (int reg = 0; reg < 4; ++reg) rowsum[m][reg] = 0.f;

#pragma unroll
  for (int m = 0; m < 4; ++m) {
#pragma unroll
    for (int n = 0; n < 4; ++n) {
      int col = col0 + wcol * 64 + n * 16 + lr;
      float av = addvb[col];
      float wo = w_out[col];
#pragma unroll
      for (int reg = 0; reg < 4; ++reg) {
        float v = acc[m][n][reg] + av;
        rowsum[m][reg] += fast_tanh(v) * wo;
      }
    }
  }
  // reduce across the 16 lanes of each lane-group (cols)
#pragma unroll
  for (int m = 0; m < 4; ++m)
#pragma unroll
    for (int reg = 0; reg < 4; ++reg) {
      float v = rowsum[m][reg];
      v += __shfl_xor(v, 1, 64);
      v += __shfl_xor(v, 2, 64);
      v += __shfl_xor(v, 4, 64);
      v += __shfl_xor(v, 8, 64);
      rowsum[m][reg] = v;
    }
  if (lr == 0) {
#pragma unroll
    for (int m = 0; m < 4; ++m)
#pragma unroll
      for (int reg = 0; reg < 4; ++reg)
        red[wrow * 64 + m * 16 + lkb * 4 + reg][wcol] = rowsum[m][reg];
  }
  __syncthreads();
  if (tid < 128)
    psc[(long)bn * 65536 + row0 + tid] = red[tid][0] + red[tid][1];
}

// ---------------- Kernel C: softmax over S=1024 per batch
__global__ __launch_bounds__(256) void softmax_kernel(const float* __restrict__ psc,
                                                      float* __restrict__ wts) {
  int b = blockIdx.x, tid = threadIdx.x;
  __shared__ float sred[8];
  float sc[4];
  float mx = -1e30f;
#pragma unroll
  for (int i = 0; i < 4; ++i) {
    long r = (long)b * 1024 + tid + i * 256;
    sc[i] = psc[r] + psc[65536 + r] + psc[2 * 65536 + r] + psc[3 * 65536 + r];
    mx = fmaxf(mx, sc[i]);
  }
  for (int off = 1; off < 64; off <<= 1) mx = fmaxf(mx, __shfl_xor(mx, off, 64));
  if ((tid & 63) == 0) sred[tid >> 6] = mx;
  __syncthreads();
  mx = fmaxf(fmaxf(sred[0], sred[1]), fmaxf(sred[2], sred[3]));
  float e[4], sum = 0.f;
#pragma unroll
  for (int i = 0; i < 4; ++i) {
    e[i] = __expf(sc[i] - mx);
    sum += e[i];
  }
  for (int off = 1; off < 64; off <<= 1) sum += __shfl_xor(sum, off, 64);
  if ((tid & 63) == 0) sred[4 + (tid >> 6)] = sum;
  __syncthreads();
  sum = sred[4] + sred[5] + sred[6] + sred[7];
  float inv = 1.f / sum;
#pragma unroll
  for (int i = 0; i < 4; ++i) wts[(long)b * 1024 + tid + i * 256] = e[i] * inv;
}

// ---------------- Kernel D: attention partials: attp[b][chunk][h] = sum_{s in chunk} w[s]*encoded[b,s,h]
__global__ __launch_bounds__(256) void att_part_kernel(const float* __restrict__ encoded,
                                                       const float* __restrict__ wts,
                                                       float* __restrict__ attp) {
  int chunk = blockIdx.x;  // 16
  int b = blockIdx.y;      // 64
  int tid = threadIdx.x;
  f32x4 acc = (f32x4){0.f, 0.f, 0.f, 0.f};
  const float* base = encoded + ((long)b * 1024 + chunk * 64) * 1024 + tid * 4;
  const float* w = wts + b * 1024 + chunk * 64;
#pragma unroll 4
  for (int s = 0; s < 64; ++s) {
    float ww = w[s];
    f32x4 v = *(const f32x4*)(base + (long)s * 1024);
    acc += v * ww;
  }
  *(f32x4*)(attp + ((long)(b * 16 + chunk)) * 1024 + tid * 4) = acc;
}

// ---------------- Kernel E: xcat[b][0:512]=inputs, xcat[b][512:1536]=sum_chunk attp
__global__ __launch_bounds__(256) void xcat_kernel(const float* __restrict__ inputs,
                                                   const float* __restrict__ attp,
                                                   float* __restrict__ xcat) {
  int b = blockIdx.y;
  int k = blockIdx.x * 256 + threadIdx.x;  // 0..1535
  float v;
  if (k < 512) {
    v = inputs[b * 512 + k];
  } else {
    int h = k - 512;
    v = 0.f;
#pragma unroll
    for (int c = 0; c < 16; ++c) v += attp[((long)(b * 16 + c)) * 1024 + h];
  }
  xcat[(long)b * 1536 + k] = v;
}

// ---------------- Kernel F: GRU GEMVs, gi = x@W_ih+b_ih, gh = states@W_hh+b_hh
// grid (64 b, 12 chunks) -> chunk-major-ish L2 reuse of W columns
__global__ __launch_bounds__(256) void gru_gemv_kernel(
    const float* __restrict__ xcat, const float* __restrict__ states,
    const float* __restrict__ W_ih, const float* __restrict__ b_ih,
    const float* __restrict__ W_hh, const float* __restrict__ b_hh,
    float* __restrict__ gi, float* __restrict__ gh) {
  int b = blockIdx.x;      // 64
  int chunk = blockIdx.y;  // 12
  int tid = threadIdx.x;
  int col = chunk * 256 + tid;  // 0..3071
  __shared__ float xl[1536];
  __shared__ float sl[1024];
  for (int i = tid; i < 1536; i += 256) xl[i] = xcat[(long)b * 1536 + i];
  for (int i = tid; i < 1024; i += 256) sl[i] = states[b * 1024 + i];
  __syncthreads();
  float ai = b_ih[col], ah = b_hh[col];
#pragma unroll 8
  for (int k = 0; k < 1536; ++k) ai += xl[k] * W_ih[(long)k * 3072 + col];
#pragma unroll 8
  for (int k = 0; k < 1024; ++k) ah += sl[k] * W_hh[(long)k * 3072 + col];
  gi[(long)b * 3072 + col] = ai;
  gh[(long)b * 3072 + col] = ah;
}

// ---------------- Kernel G: gates
__global__ __launch_bounds__(256) void gate_kernel(const float* __restrict__ gi,
                                                   const float* __restrict__ gh,
                                                   const float* __restrict__ states,
                                                   float* __restrict__ out) {
  int b = blockIdx.y;
  int j = blockIdx.x * 256 + threadIdx.x;  // 0..1023
  long o = (long)b * 3072;
  float ir = gi[o + j], hr = gh[o + j];
  float iz = gi[o + 1024 + j], hz = gh[o + 1024 + j];
  float in_ = gi[o + 2048 + j], hn = gh[o + 2048 + j];
  float r = 1.f / (1.f + __expf(-(ir + hr)));
  float z = 1.f / (1.f + __expf(-(iz + hz)));
  float n = fast_tanh(in_ + r * hn);
  out[(long)b * 1024 + j] = (1.f - z) * n + z * states[(long)b * 1024 + j];
}

extern "C" void kernel_launch(void* const* d_in, const int* in_sizes, int n_in,
                              void* d_out, int out_size, void* d_ws, size_t ws_size,
                              hipStream_t stream) {
  const float* inputs  = (const float*)d_in[0];
  const float* states  = (const float*)d_in[1];
  const float* encoded = (const float*)d_in[2];
  const float* W_enc   = (const float*)d_in[3];
  const float* b_enc   = (const float*)d_in[4];
  const float* W_dec   = (const float*)d_in[5];
  const float* b_dec   = (const float*)d_in[6];
  const float* w_out   = (const float*)d_in[7];
  // d_in[8] = b_out: softmax-invariant constant shift, unused
  const float* W_ih    = (const float*)d_in[9];
  const float* b_ih    = (const float*)d_in[10];
  const float* W_hh    = (const float*)d_in[11];
  const float* b_hh    = (const float*)d_in[12];
  float* out = (float*)d_out;
  float* ws = (float*)d_ws;

  float* addv = ws;                  // 64*512          = 32768
  float* psc  = ws + 32768;          // 4*65536         = 262144
  float* wts  = ws + 294912;         // 64*1024         = 65536
  float* attp = ws + 360448;         // 64*16*1024      = 1048576
  float* xcat = ws + 1409024;        // 64*1536         = 98304
  float* gi   = ws + 1507328;        // 64*3072         = 196608
  float* gh   = ws + 1703936;        // 64*3072         = 196608
  // total 1900544 floats = 7.25 MB

  dec_proj_kernel<<<64, 256, 0, stream>>>(states, W_dec, b_enc, b_dec, addv);

  dim3 gB(4, 512);
  enc_score_kernel<<<gB, 256, 0, stream>>>(encoded, W_enc, addv, w_out, psc);

  softmax_kernel<<<64, 256, 0, stream>>>(psc, wts);

  dim3 gD(16, 64);
  att_part_kernel<<<gD, 256, 0, stream>>>(encoded, wts, attp);

  dim3 gE(6, 64);
  xcat_kernel<<<gE, 256, 0, stream>>>(inputs, attp, xcat);

  dim3 gF(64, 12);
  gru_gemv_kernel<<<gF, 256, 0, stream>>>(xcat, states, W_ih, b_ih, W_hh, b_hh, gi, gh);

  dim3 gG(4, 64);
  gate_kernel<<<gG, 64 * 4, 0, stream>>>(gi, gh, states, out);
}

// Round 2
// 324.710 us; speedup vs baseline: 1.4211x; 1.4211x over previous
//
#include <hip/hip_runtime.h>
#include <hip/hip_bf16.h>

// Problem: B=64, S=1024, H=1024, A=512, E=512
// scores = tanh(encoded@W_enc + b_enc + states@W_dec + b_dec) . w_out (+b_out: softmax-invariant)
// weights = softmax(scores); attention = weights . encoded
// GRU: x=[inputs,attention]; gi=x@W_ih+b_ih; gh=states@W_hh+b_hh; gates -> h_new

typedef __attribute__((ext_vector_type(8))) __bf16 bf16x8;
typedef __attribute__((ext_vector_type(4))) __bf16 bf16x4;
typedef __attribute__((ext_vector_type(4))) float f32x4;

__device__ __forceinline__ float fast_tanh(float x) {
  float xa = fminf(fmaxf(x, -15.f), 15.f);
  float e = __expf(2.f * xa);
  return (e - 1.f) / (e + 1.f);
}

// ---------------- Kernel T: transpose+convert W_enc [1024][512] f32 -> Wt [512][1024] bf16
__global__ __launch_bounds__(256) void wenc_t_kernel(const float* __restrict__ W,
                                                     __bf16* __restrict__ Wt) {
  __shared__ float tile[32][33];
  int k0 = blockIdx.x * 32, a0 = blockIdx.y * 32;
  int tid = threadIdx.x;
  int r = tid >> 3, c4 = (tid & 7) * 4;
  f32x4 v = *(const f32x4*)(W + (long)(k0 + r) * 512 + a0 + c4);
  tile[r][c4 + 0] = v.x; tile[r][c4 + 1] = v.y;
  tile[r][c4 + 2] = v.z; tile[r][c4 + 3] = v.w;
  __syncthreads();
  int a = tid >> 3, k4 = (tid & 7) * 4;
  bf16x4 o = { (__bf16)tile[k4 + 0][a], (__bf16)tile[k4 + 1][a],
               (__bf16)tile[k4 + 2][a], (__bf16)tile[k4 + 3][a] };
  *(bf16x4*)(Wt + (long)(a0 + a) * 1024 + k0 + k4) = o;
}

// ---------------- Kernel A: addv[b][a] = b_enc[a]+b_dec[a]+sum_h states[b,h]*W_dec[h,a]
__global__ __launch_bounds__(256) void dec_proj_kernel(
    const float* __restrict__ states, const float* __restrict__ W_dec,
    const float* __restrict__ b_enc, const float* __restrict__ b_dec,
    float* __restrict__ addv) {
  int b = blockIdx.x, tid = threadIdx.x;
  int a = blockIdx.y * 256 + tid;
  __shared__ float sl[1024];
  for (int i = tid; i < 1024; i += 256) sl[i] = states[b * 1024 + i];
  __syncthreads();
  float c0 = 0.f, c1 = 0.f, c2 = 0.f, c3 = 0.f;
#pragma unroll 4
  for (int i = 0; i < 256; ++i) {
    c0 += sl[i]         * W_dec[(i)        * 512 + a];
    c1 += sl[i + 256]   * W_dec[(i + 256)  * 512 + a];
    c2 += sl[i + 512]   * W_dec[(i + 512)  * 512 + a];
    c3 += sl[i + 768]   * W_dec[(i + 768)  * 512 + a];
  }
  addv[b * 512 + a] = c0 + c1 + c2 + c3 + b_enc[a] + b_dec[a];
}

// ---------------- Kernel B: 128x128 tile, BK=64, 8 waves (2x4), XOR-swizzled LDS,
// dbuf + 1 barrier, XCD-pinned bn-siblings, fused tanh/w_out row-reduce epilogue.
__global__ __launch_bounds__(512) void enc_score_kernel(
    const float* __restrict__ encoded,  // [65536][1024] f32
    const __bf16* __restrict__ Wt,      // [512][1024] bf16 (W_enc^T)
    const float* __restrict__ addv,     // [64][512]
    const float* __restrict__ w_out,    // [512]
    float* __restrict__ psc)            // [4][65536]
{
  __shared__ __attribute__((aligned(16))) char smem[67584];
  char* Abase = smem;            // 2 x 128 rows x 128 B
  char* Bbase = smem + 32768;    // 2 x 128 cols x 128 B
  float* red = (float*)(smem + 65536);  // [128][4]

  const int d = blockIdx.x;
  const int xcd = d & 7;
  const int slot = d >> 3;
  const int bn = slot & 3;
  const int bm = ((slot >> 2) << 3) | xcd;   // bn-siblings share bm AND xcd

  const int tid = threadIdx.x;
  const int lane = tid & 63;
  const int wid = tid >> 6;       // 0..7
  const int wrow = wid >> 2;      // 0..1 (64 rows each)
  const int wcol = wid & 3;       // 0..3 (32 cols each)
  const int lr = lane & 15;
  const int lkb = lane >> 4;      // 0..3

  const long row0 = (long)bm * 128;
  const int col0 = bn * 128;

  f32x4 ra[4];
  bf16x8 rb[2];

  auto loadT = [&](int kt) {
#pragma unroll
    for (int i = 0; i < 4; ++i) {
      int g = i * 512 + tid;
      int row = g >> 4, c4 = g & 15;
      ra[i] = *(const f32x4*)(encoded + (row0 + row) * 1024 + kt * 64 + c4 * 4);
    }
#pragma unroll
    for (int i = 0; i < 2; ++i) {
      int g = i * 512 + tid;
      int col = g >> 3, k8 = g & 7;
      rb[i] = *(const bf16x8*)(Wt + (long)(col0 + col) * 1024 + kt * 64 + k8 * 8);
    }
  };
  auto writeT = [&](int buf) {
#pragma unroll
    for (int i = 0; i < 4; ++i) {
      int g = i * 512 + tid;
      int row = g >> 4, c4 = g & 15;
      bf16x4 v = { (__bf16)ra[i].x, (__bf16)ra[i].y, (__bf16)ra[i].z, (__bf16)ra[i].w };
      int off = (c4 * 8) ^ ((row & 7) << 4);
      *(bf16x4*)(Abase + buf * 16384 + row * 128 + off) = v;
    }
#pragma unroll
    for (int i = 0; i < 2; ++i) {
      int g = i * 512 + tid;
      int col = g >> 3, k8 = g & 7;
      int off = (k8 * 16) ^ ((col & 7) << 4);
      *(bf16x8*)(Bbase + buf * 16384 + col * 128 + off) = rb[i];
    }
  };

  f32x4 acc[4][2];
#pragma unroll
  for (int m = 0; m < 4; ++m)
#pragma unroll
    for (int n = 0; n < 2; ++n) acc[m][n] = (f32x4){0.f, 0.f, 0.f, 0.f};

  loadT(0);
  writeT(0);
  int buf = 0;
  for (int kt = 0; kt < 16; ++kt) {
    __syncthreads();
    if (kt < 15) loadT(kt + 1);
#pragma unroll
    for (int ks = 0; ks < 2; ++ks) {
      bf16x8 af[4], bfv[2];
#pragma unroll
      for (int m = 0; m < 4; ++m) {
        int row = wrow * 64 + m * 16 + lr;
        int kb = (ks * 64 + lkb * 16) ^ ((row & 7) << 4);
        af[m] = *(const bf16x8*)(Abase + buf * 16384 + row * 128 + kb);
      }
#pragma unroll
      for (int n = 0; n < 2; ++n) {
        int col = wcol * 32 + n * 16 + lr;
        int kb = (ks * 64 + lkb * 16) ^ ((col & 7) << 4);
        bfv[n] = *(const bf16x8*)(Bbase + buf * 16384 + col * 128 + kb);
      }
#pragma unroll
      for (int m = 0; m < 4; ++m)
#pragma unroll
        for (int n = 0; n < 2; ++n)
          acc[m][n] = __builtin_amdgcn_mfma_f32_16x16x32_bf16(af[m], bfv[n], acc[m][n], 0, 0, 0);
    }
    if (kt < 15) writeT(buf ^ 1);
    buf ^= 1;
  }

  // Epilogue: per-row sum of tanh(acc + addv[b][col]) * w_out[col]
  // C/D layout: col = lane&15, row = (lane>>4)*4 + reg
  const int b = bm >> 3;
  const float* addvb = addv + b * 512;
  float rowsum[4][4];
#pragma unroll
  for (int m = 0; m < 4; ++m)
#pragma unroll
    for (int reg = 0; reg < 4; ++reg) rowsum[m][reg] = 0.f;

#pragma unroll
  for (int m = 0; m < 4; ++m) {
#pragma unroll
    for (int n = 0; n < 2; ++n) {
      int col = col0 + wcol * 32 + n * 16 + lr;
      float av = addvb[col];
      float wo = w_out[col];
#pragma unroll
      for (int reg = 0; reg < 4; ++reg)
        rowsum[m][reg] += fast_tanh(acc[m][n][reg] + av) * wo;
    }
  }
#pragma unroll
  for (int m = 0; m < 4; ++m)
#pragma unroll
    for (int reg = 0; reg < 4; ++reg) {
      float v = rowsum[m][reg];
      v += __shfl_xor(v, 1, 64);
      v += __shfl_xor(v, 2, 64);
      v += __shfl_xor(v, 4, 64);
      v += __shfl_xor(v, 8, 64);
      rowsum[m][reg] = v;
    }
  if (lr == 0) {
#pragma unroll
    for (int m = 0; m < 4; ++m)
#pragma unroll
      for (int reg = 0; reg < 4; ++reg)
        red[(wrow * 64 + m * 16 + lkb * 4 + reg) * 4 + wcol] = rowsum[m][reg];
  }
  __syncthreads();
  if (tid < 128)
    psc[(long)bn * 65536 + row0 + tid] =
        red[tid * 4] + red[tid * 4 + 1] + red[tid * 4 + 2] + red[tid * 4 + 3];
}

// ---------------- Kernel C: softmax over S=1024 per batch
__global__ __launch_bounds__(256) void softmax_kernel(const float* __restrict__ psc,
                                                      float* __restrict__ wts) {
  int b = blockIdx.x, tid = threadIdx.x;
  __shared__ float sred[8];
  float sc[4];
  float mx = -1e30f;
#pragma unroll
  for (int i = 0; i < 4; ++i) {
    long r = (long)b * 1024 + tid + i * 256;
    sc[i] = psc[r] + psc[65536 + r] + psc[2 * 65536 + r] + psc[3 * 65536 + r];
    mx = fmaxf(mx, sc[i]);
  }
  for (int off = 1; off < 64; off <<= 1) mx = fmaxf(mx, __shfl_xor(mx, off, 64));
  if ((tid & 63) == 0) sred[tid >> 6] = mx;
  __syncthreads();
  mx = fmaxf(fmaxf(sred[0], sred[1]), fmaxf(sred[2], sred[3]));
  float e[4], sum = 0.f;
#pragma unroll
  for (int i = 0; i < 4; ++i) {
    e[i] = __expf(sc[i] - mx);
    sum += e[i];
  }
  for (int off = 1; off < 64; off <<= 1) sum += __shfl_xor(sum, off, 64);
  if ((tid & 63) == 0) sred[4 + (tid >> 6)] = sum;
  __syncthreads();
  sum = sred[4] + sred[5] + sred[6] + sred[7];
  float inv = 1.f / sum;
#pragma unroll
  for (int i = 0; i < 4; ++i) wts[(long)b * 1024 + tid + i * 256] = e[i] * inv;
}

// ---------------- Kernel D: attention partials over 8 chunks of 128 s
__global__ __launch_bounds__(256) void att_part_kernel(const float* __restrict__ encoded,
                                                       const float* __restrict__ wts,
                                                       float* __restrict__ attp) {
  int chunk = blockIdx.x;  // 8
  int b = blockIdx.y;      // 64
  int tid = threadIdx.x;
  f32x4 acc0 = (f32x4){0.f, 0.f, 0.f, 0.f};
  f32x4 acc1 = (f32x4){0.f, 0.f, 0.f, 0.f};
  const float* base = encoded + ((long)b * 1024 + chunk * 128) * 1024 + tid * 4;
  const float* w = wts + b * 1024 + chunk * 128;
#pragma unroll 4
  for (int s = 0; s < 128; s += 2) {
    acc0 += *(const f32x4*)(base + (long)s * 1024) * w[s];
    acc1 += *(const f32x4*)(base + (long)(s + 1) * 1024) * w[s + 1];
  }
  *(f32x4*)(attp + ((long)(b * 8 + chunk)) * 1024 + tid * 4) = acc0 + acc1;
}

// ---------------- Kernel E: xcat[b][0:512]=inputs, xcat[b][512:1536]=sum_chunk attp
__global__ __launch_bounds__(256) void xcat_kernel(const float* __restrict__ inputs,
                                                   const float* __restrict__ attp,
                                                   float* __restrict__ xcat) {
  int b = blockIdx.y;
  int k = blockIdx.x * 256 + threadIdx.x;  // 0..1535
  float v;
  if (k < 512) {
    v = inputs[b * 512 + k];
  } else {
    int h = k - 512;
    v = 0.f;
#pragma unroll
    for (int c = 0; c < 8; ++c) v += attp[((long)(b * 8 + c)) * 1024 + h];
  }
  xcat[(long)b * 1536 + k] = v;
}

// ---------------- Kernel F: GRU GEMVs, batch-grouped: 24 chunk-groups x 8 batch-groups,
// chunk-group pinned to one XCD so its 8 siblings share the W columns in L2.
__global__ __launch_bounds__(512) void gru_gemv_kernel(
    const float* __restrict__ xcat, const float* __restrict__ states,
    const float* __restrict__ W_ih, const float* __restrict__ b_ih,
    const float* __restrict__ W_hh, const float* __restrict__ b_hh,
    float* __restrict__ gi, float* __restrict__ gh) {
  __shared__ float sx[12288];  // 8 batches x 1536 (max)
  const int dd = blockIdx.x;          // 192
  const int xcd = dd & 7;
  const int n = dd >> 3;              // 0..23
  const int cgrp = xcd + 8 * (n >> 3);  // 0..23, pinned to xcd
  const int bg = n & 7;
  const int tid = threadIdx.x;
  const int lcol = tid & 255;
  const int bsel = (tid >> 8) * 4;    // 0 or 4

  if (cgrp < 12) {
    const int col = cgrp * 256 + lcol;
    const float* xb = xcat + (long)bg * 8 * 1536;
    for (int i = tid; i < 3072; i += 512) ((f32x4*)sx)[i] = ((const f32x4*)xb)[i];
    __syncthreads();
    float a0 = b_ih[col], a1 = a0, a2 = a0, a3 = a0;
    const float* x0 = sx + (bsel + 0) * 1536;
    const float* x1 = sx + (bsel + 1) * 1536;
    const float* x2 = sx + (bsel + 2) * 1536;
    const float* x3 = sx + (bsel + 3) * 1536;
    for (int k = 0; k < 1536; k += 4) {
      f32x4 v0 = *(const f32x4*)(x0 + k);
      f32x4 v1 = *(const f32x4*)(x1 + k);
      f32x4 v2 = *(const f32x4*)(x2 + k);
      f32x4 v3 = *(const f32x4*)(x3 + k);
#pragma unroll
      for (int j = 0; j < 4; ++j) {
        float w = W_ih[(long)(k + j) * 3072 + col];
        a0 += v0[j] * w; a1 += v1[j] * w; a2 += v2[j] * w; a3 += v3[j] * w;
      }
    }
    long o = (long)(bg * 8 + bsel) * 3072 + col;
    gi[o] = a0; gi[o + 3072] = a1; gi[o + 6144] = a2; gi[o + 9216] = a3;
  } else {
    const int col = (cgrp - 12) * 256 + lcol;
    const float* sb = states + (long)bg * 8 * 1024;
    for (int i = tid; i < 2048; i += 512) ((f32x4*)sx)[i] = ((const f32x4*)sb)[i];
    __syncthreads();
    float a0 = b_hh[col], a1 = a0, a2 = a0, a3 = a0;
    const float* x0 = sx + (bsel + 0) * 1024;
    const float* x1 = sx + (bsel + 1) * 1024;
    const float* x2 = sx + (bsel + 2) * 1024;
    const float* x3 = sx + (bsel + 3) * 1024;
    for (int k = 0; k < 1024; k += 4) {
      f32x4 v0 = *(const f32x4*)(x0 + k);
      f32x4 v1 = *(const f32x4*)(x1 + k);
      f32x4 v2 = *(const f32x4*)(x2 + k);
      f32x4 v3 = *(const f32x4*)(x3 + k);
#pragma unroll
      for (int j = 0; j < 4; ++j) {
        float w = W_hh[(long)(k + j) * 3072 + col];
        a0 += v0[j] * w; a1 += v1[j] * w; a2 += v2[j] * w; a3 += v3[j] * w;
      }
    }
    long o = (long)(bg * 8 + bsel) * 3072 + col;
    gh[o] = a0; gh[o + 3072] = a1; gh[o + 6144] = a2; gh[o + 9216] = a3;
  }
}

// ---------------- Kernel G: gates
__global__ __launch_bounds__(256) void gate_kernel(const float* __restrict__ gi,
                                                   const float* __restrict__ gh,
                                                   const float* __restrict__ states,
                                                   float* __restrict__ out) {
  int b = blockIdx.y;
  int j = blockIdx.x * 256 + threadIdx.x;  // 0..1023
  long o = (long)b * 3072;
  float ir = gi[o + j], hr = gh[o + j];
  float iz = gi[o + 1024 + j], hz = gh[o + 1024 + j];
  float in_ = gi[o + 2048 + j], hn = gh[o + 2048 + j];
  float r = 1.f / (1.f + __expf(-(ir + hr)));
  float z = 1.f / (1.f + __expf(-(iz + hz)));
  float n = fast_tanh(in_ + r * hn);
  out[(long)b * 1024 + j] = (1.f - z) * n + z * states[(long)b * 1024 + j];
}

extern "C" void kernel_launch(void* const* d_in, const int* in_sizes, int n_in,
                              void* d_out, int out_size, void* d_ws, size_t ws_size,
                              hipStream_t stream) {
  const float* inputs  = (const float*)d_in[0];
  const float* states  = (const float*)d_in[1];
  const float* encoded = (const float*)d_in[2];
  const float* W_enc   = (const float*)d_in[3];
  const float* b_enc   = (const float*)d_in[4];
  const float* W_dec   = (const float*)d_in[5];
  const float* b_dec   = (const float*)d_in[6];
  const float* w_out   = (const float*)d_in[7];
  // d_in[8] = b_out: softmax-invariant, unused
  const float* W_ih    = (const float*)d_in[9];
  const float* b_ih    = (const float*)d_in[10];
  const float* W_hh    = (const float*)d_in[11];
  const float* b_hh    = (const float*)d_in[12];
  float* out = (float*)d_out;
  float* ws = (float*)d_ws;

  float* addv = ws;                 // 32768
  float* psc  = ws + 32768;         // 262144
  float* wts  = ws + 294912;        // 65536
  float* attp = ws + 360448;        // 64*8*1024 = 524288
  float* xcat = ws + 884736;        // 98304
  float* gi   = ws + 983040;        // 196608
  float* gh   = ws + 1179648;       // 196608
  __bf16* Wt  = (__bf16*)(ws + 1376256);  // 512*1024 bf16 (262144 float slots)
  // total 1638400 floats = 6.55 MB

  wenc_t_kernel<<<dim3(32, 16), 256, 0, stream>>>(W_enc, Wt);

  dim3 gA(64, 2);
  dec_proj_kernel<<<gA, 256, 0, stream>>>(states, W_dec, b_enc, b_dec, addv);

  enc_score_kernel<<<2048, 512, 0, stream>>>(encoded, Wt, addv, w_out, psc);

  softmax_kernel<<<64, 256, 0, stream>>>(psc, wts);

  dim3 gD(8, 64);
  att_part_kernel<<<gD, 256, 0, stream>>>(encoded, wts, attp);

  dim3 gE(6, 64);
  xcat_kernel<<<gE, 256, 0, stream>>>(inputs, attp, xcat);

  gru_gemv_kernel<<<192, 512, 0, stream>>>(xcat, states, W_ih, b_ih, W_hh, b_hh, gi, gh);

  dim3 gG(4, 64);
  gate_kernel<<<gG, 256, 0, stream>>>(gi, gh, states, out);
}